// Round 5
// baseline (325.973 us; speedup 1.0000x reference)
//
#include <hip/hip_runtime.h>
#include <hip/hip_bf16.h>

// Problem constants
#define BATCH 256
#define DIM   2048
#define NMEM  16384   // C_CAM * P
#define PCLS  2048
#define CCAM  8
#define KSEL  50
#define T_INV 14.285714285714285714f   // 1 / 0.07
#define NBIN  4096

typedef __bf16 bf16x8 __attribute__((ext_vector_type(8)));
typedef float  f32x4  __attribute__((ext_vector_type(4)));

static __device__ __forceinline__ unsigned int f2bf(float f) {
  unsigned int u = __float_as_uint(f);
  return (u + 0x7FFFu + ((u >> 16) & 1u)) >> 16;   // RNE truncate to bf16
}
static __device__ __forceinline__ unsigned int pk2(float lo, float hi) {
  return f2bf(lo) | (f2bf(hi) << 16);
}
// logits are cosine sims in [-1,1]; map to bin 0..4095 (masked -1e30 -> bin 0)
static __device__ __forceinline__ int binof(float v) {
  float bf = fmaf(v, 1950.4762f, 2048.0f);     // 4096 / 2.1 scale
  bf = fminf(fmaxf(bf, 0.0f), 4095.0f);
  return (int)bf;
}

// ---------------------------------------------------------------------------
// Kernel 1: row-normalize inputs, cast to bf16.  grid=256 blocks x 256 thr
// ---------------------------------------------------------------------------
__global__ __launch_bounds__(256) void norm_cast_kernel(
    const float* __restrict__ in, unsigned short* __restrict__ xb) {
  __shared__ float red[256];
  const int b = blockIdx.x, t = threadIdx.x;
  const float4* row = (const float4*)(in + (size_t)b * DIM);
  float4 a0 = row[t];
  float4 a1 = row[t + 256];
  float ss = a0.x*a0.x + a0.y*a0.y + a0.z*a0.z + a0.w*a0.w
           + a1.x*a1.x + a1.y*a1.y + a1.z*a1.z + a1.w*a1.w;
  red[t] = ss; __syncthreads();
  for (int s = 128; s > 0; s >>= 1) { if (t < s) red[t] += red[t + s]; __syncthreads(); }
  const float rn = rsqrtf(red[0]);
  ushort4 o0, o1;
  o0.x = (unsigned short)f2bf(a0.x*rn); o0.y = (unsigned short)f2bf(a0.y*rn);
  o0.z = (unsigned short)f2bf(a0.z*rn); o0.w = (unsigned short)f2bf(a0.w*rn);
  o1.x = (unsigned short)f2bf(a1.x*rn); o1.y = (unsigned short)f2bf(a1.y*rn);
  o1.z = (unsigned short)f2bf(a1.z*rn); o1.w = (unsigned short)f2bf(a1.w*rn);
  *(ushort4*)&xb[(size_t)b * DIM + t * 4]         = o0;
  *(ushort4*)&xb[(size_t)b * DIM + (t + 256) * 4] = o1;
}

// ---------------------------------------------------------------------------
// Kernel 2: logits = x(bf16) @ tempV^T  (tempV fp32, converted in staging)
// BM=128, BN=64, BK=64. 256 threads = 4 waves (2Mx2N), wave tile 64x32.
// Double-buffered LDS + 2-tile-deep register prefetch: one barrier per
// K-tile; loads for tile k+2 issued while computing tile k (~2 compute
// phases of latency cover). grid = dim3(2, 256) -> 2 blocks/CU.
// ---------------------------------------------------------------------------
#define BM 128
#define BN 64
#define BK 64
#define LDT 72   // padded LDS row stride (bf16 elems): 64 + 8
#define NTILE (DIM / BK)   // 32

__global__ __launch_bounds__(256, 2) void gemm_kernel(
    const unsigned short* __restrict__ X,   // [256][2048] bf16
    const float* __restrict__ V,            // [16384][2048] fp32
    float* __restrict__ C) {                // [256][16384] fp32
  __shared__ unsigned short As[2][BM * LDT];   // 2 x 18 KB
  __shared__ unsigned short Bs[2][BN * LDT];   // 2 x 9 KB
  const int t  = threadIdx.x;
  const int m0 = blockIdx.x * BM;
  const int n0 = blockIdx.y * BN;
  const int lane = t & 63;
  const int w    = t >> 6;
  const int wm   = (w >> 1) * 64;   // 0,64
  const int wn   = (w & 1) * 32;    // 0,32

  f32x4 acc[4][2];
#pragma unroll
  for (int i = 0; i < 4; i++)
#pragma unroll
    for (int j = 0; j < 2; j++) acc[i][j] = (f32x4){0.f, 0.f, 0.f, 0.f};

  // staging: A -> thread covers 32 bf16 of one row (128 rows x 2 halves)
  //          B -> thread covers 16 fp32 of one row  (64 rows x 4 quarters)
  const int sr = t >> 1;            // 0..127
  const int sh = (t & 1) * 32;
  const int rb = t >> 2;            // 0..63
  const int cb = (t & 3) * 16;
  const unsigned short* Xp = X + (size_t)(m0 + sr) * DIM + sh;
  const float*          Vp = V + (size_t)(n0 + rb) * DIM + cb;

  const int fr = lane & 15;
  const int fk = (lane >> 4) * 8;

  uint4  xa[2][4];
  float4 vb[2][4];

  // lambda helpers -----------------------------------------------------------
  auto loadset = [&](int set, int koff) {
#pragma unroll
    for (int q = 0; q < 4; q++) xa[set][q] = *(const uint4*)(Xp + koff + q * 8);
#pragma unroll
    for (int q = 0; q < 4; q++) vb[set][q] = *(const float4*)(Vp + koff + q * 4);
  };
  auto stage = [&](int set, int buf) {
    *(uint4*)&As[buf][sr * LDT + sh]      = xa[set][0];
    *(uint4*)&As[buf][sr * LDT + sh + 8]  = xa[set][1];
    *(uint4*)&As[buf][sr * LDT + sh + 16] = xa[set][2];
    *(uint4*)&As[buf][sr * LDT + sh + 24] = xa[set][3];
    uint4 p0, p1;
    p0.x = pk2(vb[set][0].x, vb[set][0].y); p0.y = pk2(vb[set][0].z, vb[set][0].w);
    p0.z = pk2(vb[set][1].x, vb[set][1].y); p0.w = pk2(vb[set][1].z, vb[set][1].w);
    p1.x = pk2(vb[set][2].x, vb[set][2].y); p1.y = pk2(vb[set][2].z, vb[set][2].w);
    p1.z = pk2(vb[set][3].x, vb[set][3].y); p1.w = pk2(vb[set][3].z, vb[set][3].w);
    *(uint4*)&Bs[buf][rb * LDT + cb]     = p0;
    *(uint4*)&Bs[buf][rb * LDT + cb + 8] = p1;
  };
  auto compute = [&](int buf) {
#pragma unroll
    for (int kk = 0; kk < BK; kk += 32) {
      bf16x8 aF[4], bF[2];
#pragma unroll
      for (int i = 0; i < 4; i++)
        aF[i] = *(const bf16x8*)&As[buf][(wm + i * 16 + fr) * LDT + kk + fk];
#pragma unroll
      for (int j = 0; j < 2; j++)
        bF[j] = *(const bf16x8*)&Bs[buf][(wn + j * 16 + fr) * LDT + kk + fk];
#pragma unroll
      for (int i = 0; i < 4; i++)
#pragma unroll
        for (int j = 0; j < 2; j++)
          acc[i][j] = __builtin_amdgcn_mfma_f32_16x16x32_bf16(aF[i], bF[j], acc[i][j], 0, 0, 0);
    }
  };
  // ---------------------------------------------------------------------------

  // prologue: tiles 0,1 into register sets; tile 0 into LDS buf 0
  loadset(0, 0);
  loadset(1, BK);
  stage(0, 0);
  __syncthreads();

  for (int j = 0; j < NTILE / 2; j++) {
    const int base = j * 2 * BK;
    // ---- phase A: compute tile 2j (buf0); set0 free -> prefetch tile 2j+2
    if (base + 2 * BK < DIM) loadset(0, base + 2 * BK);
    compute(0);
    stage(1, 1);           // tile 2j+1 -> buf1 (vmcnt waits on set1's loads)
    __syncthreads();
    // ---- phase B: compute tile 2j+1 (buf1); set1 free -> prefetch tile 2j+3
    if (base + 3 * BK < DIM) loadset(1, base + 3 * BK);
    compute(1);
    if (base + 2 * BK < DIM) {
      stage(0, 0);         // tile 2j+2 -> buf0
      __syncthreads();
    }
  }

  // epilogue: C/D layout col=lane&15, row=(lane>>4)*4+reg  [m89/m91 verified]
  const int cr = (lane >> 4) * 4;
  const int cc = lane & 15;
#pragma unroll
  for (int i = 0; i < 4; i++)
#pragma unroll
    for (int j = 0; j < 2; j++)
#pragma unroll
      for (int r = 0; r < 4; r++)
        C[(size_t)(m0 + wm + i * 16 + cr + r) * NMEM + (n0 + wn + j * 16 + cc)] =
            acc[i][j][r];
}

// ---------------------------------------------------------------------------
// Kernel 3: per-row losses. One block (256 thr) per sample.
//  - intra CE over own camera bank (no max-sub: exp(v*14.3) <= 1.6e6, fp32 ok)
//  - mask 8 positives
//  - EXACT top-50 via 4096-bin LDS histogram + suffix scan; bins above the
//    boundary bin sum directly, boundary bin resolved exactly (few elems)
//  - inter logsumexp over {8 ori, 50 sel}
// ---------------------------------------------------------------------------
__global__ __launch_bounds__(256) void row_loss_kernel(
    const float* __restrict__ logits,
    const int* __restrict__ labels, const int* __restrict__ cams,
    float* __restrict__ ce_out, float* __restrict__ lossk_out) {
  __shared__ float vals[NMEM];      // 64 KB
  __shared__ int   hist[NBIN];      // 16 KB
  __shared__ float red[256];
  __shared__ int   pint[256];
  __shared__ float bl[512];         // boundary-bin value list
  __shared__ int   bcount;
  __shared__ int   bstar_s, cabove_s;

  const int b = blockIdx.x, t = threadIdx.x;
  const float4* src = (const float4*)(logits + (size_t)b * NMEM);
#pragma unroll
  for (int i = 0; i < 16; i++) ((float4*)vals)[t + 256 * i] = src[t + 256 * i];
#pragma unroll
  for (int i = 0; i < NBIN / 256; i++) hist[t + 256 * i] = 0;
  if (t == 0) bcount = 0;
  const int cam = cams[b], label = labels[b];
  __syncthreads();

  // ---- intra CE over [cam*PCLS, +PCLS) ----
  const int s0 = cam * PCLS;
  float S = 0.f;
#pragma unroll
  for (int i = 0; i < 8; i++) S += __expf(vals[s0 + t + 256 * i] * T_INV);
  red[t] = S; __syncthreads();
  for (int s = 128; s > 0; s >>= 1) { if (t < s) red[t] += red[t + s]; __syncthreads(); }
  float ov[CCAM]; float sumo = 0.f;
  if (t == 0) {
    ce_out[b] = logf(red[0]) - vals[s0 + label] * T_INV;
#pragma unroll
    for (int c = 0; c < CCAM; c++) { ov[c] = vals[c * PCLS + label]; sumo += ov[c]; }
  }
  __syncthreads();                 // t0's ov reads done before masking
  if (t < CCAM) vals[t * PCLS + label] = -1e30f;
  __syncthreads();

  // ---- histogram ----
#pragma unroll
  for (int i = 0; i < 64; i++) {
    int bin = binof(vals[t + 256 * i]);
    atomicAdd(&hist[bin], 1);
  }
  __syncthreads();

  // ---- suffix scan: find boundary bin b* with S(b*) >= K > S(b*+1) ----
  int ps = 0;
#pragma unroll
  for (int i = 0; i < 16; i++) ps += hist[t * 16 + i];
  pint[t] = ps; __syncthreads();
  if (t == 0) {
    int cum = 0, bstar = 0, cab = 0;
    for (int tc = 255; tc >= 0; tc--) {
      if (cum + pint[tc] >= KSEL) {
        for (int bi = tc * 16 + 15; bi >= tc * 16; bi--) {
          int h = hist[bi];
          if (cum + h >= KSEL) { bstar = bi; cab = cum; break; }
          cum += h;
        }
        break;
      }
      cum += pint[tc];
    }
    bstar_s = bstar; cabove_s = cab;
  }
  __syncthreads();
  const int bstar = bstar_s;

  // ---- selection pass: sum exp over bins > b*, collect boundary bin ----
  float S2 = 0.f;
#pragma unroll
  for (int i = 0; i < 64; i++) {
    float v = vals[t + 256 * i];
    int bin = binof(v);
    if (bin > bstar) S2 += __expf(v * T_INV);
    else if (bin == bstar) {
      int p = atomicAdd(&bcount, 1);
      if (p < 512) bl[p] = v;
    }
  }
  red[t] = S2; __syncthreads();
  for (int s = 128; s > 0; s >>= 1) { if (t < s) red[t] += red[t + s]; __syncthreads(); }

  if (t == 0) {
    float S2tot = red[0];
    int need = KSEL - cabove_s;
    int bc = min(bcount, 512);
    for (int r = 0; r < need; r++) {         // exact top-(need) of boundary bin
      float mx = -1e30f; int mi = 0;
      for (int i = 0; i < bc; i++) if (bl[i] > mx) { mx = bl[i]; mi = i; }
      S2tot += __expf(mx * T_INV);
      bl[mi] = -1e30f;
    }
#pragma unroll
    for (int c = 0; c < CCAM; c++) S2tot += __expf(ov[c] * T_INV);
    lossk_out[b] = logf(S2tot) - (sumo * T_INV) * (1.0f / CCAM);
  }
}

// ---------------------------------------------------------------------------
// Kernel 4: deterministic per-camera segment means -> 2 scalars.
// ---------------------------------------------------------------------------
__global__ __launch_bounds__(256) void finalize_kernel(
    const float* __restrict__ ce, const float* __restrict__ lossk,
    const int* __restrict__ cams, float* __restrict__ out) {
  __shared__ float ce_s[BATCH], lk_s[BATCH];
  __shared__ int   cam_s[BATCH];
  __shared__ float si[CCAM], sk[CCAM], cnt[CCAM];
  const int t = threadIdx.x;
  ce_s[t]  = ce[t];
  lk_s[t]  = lossk[t];
  cam_s[t] = cams[t];
  __syncthreads();
  if (t < CCAM) {
    float a = 0.f, b = 0.f; int n = 0;
    for (int i = 0; i < BATCH; i++) {
      if (cam_s[i] == t) { a += ce_s[i]; b += lk_s[i]; n++; }
    }
    si[t] = a; sk[t] = b; cnt[t] = (float)n;
  }
  __syncthreads();
  if (t == 0) {
    float li = 0.f, lk = 0.f;
    for (int c = 0; c < CCAM; c++) {
      if (cnt[c] > 0.f) { li += si[c] / cnt[c]; lk += sk[c] / cnt[c]; }
    }
    out[0] = li;
    out[1] = 0.5f * lk;
  }
}

// ---------------------------------------------------------------------------
extern "C" void kernel_launch(void* const* d_in, const int* in_sizes, int n_in,
                              void* d_out, int out_size, void* d_ws, size_t ws_size,
                              hipStream_t stream) {
  const float* inputs = (const float*)d_in[0];   // [256][2048]
  const int*   labels = (const int*)d_in[1];     // [256]
  const int*   cams   = (const int*)d_in[2];     // [256]
  const float* tempV  = (const float*)d_in[3];   // [16384][2048]
  float* out = (float*)d_out;

  char* ws = (char*)d_ws;
  unsigned short* xb  = (unsigned short*)ws;                       // 1 MB
  float* logits       = (float*)(ws + (1u << 20));                 // 16 MB
  float* ce           = (float*)(ws + (1u << 20) + (16u << 20));   // 1 KB
  float* lossk        = (float*)(ws + (1u << 20) + (16u << 20) + 1024);

  norm_cast_kernel<<<BATCH, 256, 0, stream>>>(inputs, xb);
  gemm_kernel<<<dim3(BATCH / BM, NMEM / BN), 256, 0, stream>>>(xb, tempV, logits);
  row_loss_kernel<<<BATCH, 256, 0, stream>>>(logits, labels, cams, ce, lossk);
  finalize_kernel<<<1, 256, 0, stream>>>(ce, lossk, cams, out);
}

// Round 6
// 275.510 us; speedup vs baseline: 1.1832x; 1.1832x over previous
//
#include <hip/hip_runtime.h>
#include <hip/hip_bf16.h>

// Problem constants
#define BATCH 256
#define DIM   2048
#define NMEM  16384   // C_CAM * P
#define PCLS  2048
#define CCAM  8
#define KSEL  50
#define T_INV 14.285714285714285714f   // 1 / 0.07
#define NBIN  4096

typedef __bf16 bf16x8 __attribute__((ext_vector_type(8)));
typedef float  f32x4  __attribute__((ext_vector_type(4)));

#define AS_GLOBAL __attribute__((address_space(1)))
#define AS_LDS    __attribute__((address_space(3)))

static __device__ __forceinline__ unsigned int f2bf(float f) {
  unsigned int u = __float_as_uint(f);
  return (u + 0x7FFFu + ((u >> 16) & 1u)) >> 16;   // RNE truncate to bf16
}
static __device__ __forceinline__ unsigned int pk2(float lo, float hi) {
  return f2bf(lo) | (f2bf(hi) << 16);
}
// logits are cosine sims in [-1,1]; map to bin 0..4095 (masked -1e30 -> bin 0)
static __device__ __forceinline__ int binof(float v) {
  float bf = fmaf(v, 1950.4762f, 2048.0f);     // 4096 / 2.1 scale
  bf = fminf(fmaxf(bf, 0.0f), 4095.0f);
  return (int)bf;
}

// ---------------------------------------------------------------------------
// Kernel 1: row-normalize inputs, cast to bf16.  grid=256 blocks x 256 thr
// ---------------------------------------------------------------------------
__global__ __launch_bounds__(256) void norm_cast_kernel(
    const float* __restrict__ in, unsigned short* __restrict__ xb) {
  __shared__ float red[256];
  const int b = blockIdx.x, t = threadIdx.x;
  const float4* row = (const float4*)(in + (size_t)b * DIM);
  float4 a0 = row[t];
  float4 a1 = row[t + 256];
  float ss = a0.x*a0.x + a0.y*a0.y + a0.z*a0.z + a0.w*a0.w
           + a1.x*a1.x + a1.y*a1.y + a1.z*a1.z + a1.w*a1.w;
  red[t] = ss; __syncthreads();
  for (int s = 128; s > 0; s >>= 1) { if (t < s) red[t] += red[t + s]; __syncthreads(); }
  const float rn = rsqrtf(red[0]);
  ushort4 o0, o1;
  o0.x = (unsigned short)f2bf(a0.x*rn); o0.y = (unsigned short)f2bf(a0.y*rn);
  o0.z = (unsigned short)f2bf(a0.z*rn); o0.w = (unsigned short)f2bf(a0.w*rn);
  o1.x = (unsigned short)f2bf(a1.x*rn); o1.y = (unsigned short)f2bf(a1.y*rn);
  o1.z = (unsigned short)f2bf(a1.z*rn); o1.w = (unsigned short)f2bf(a1.w*rn);
  *(ushort4*)&xb[(size_t)b * DIM + t * 4]         = o0;
  *(ushort4*)&xb[(size_t)b * DIM + (t + 256) * 4] = o1;
}

// ---------------------------------------------------------------------------
// Kernel 2: logits = x(bf16) @ tempV^T, tempV staged fp32 via
// __builtin_amdgcn_global_load_lds (width 16), converted to bf16 at
// fragment-read time. BM=128, BN=64, BK=64, 256 thr = 4 waves (2Mx2N),
// wave tile 64x32. Double-buffered LDS (64 KB), one barrier per K-tile,
// grid = dim3(2, 256) -> 2 blocks/CU.
// LDS layouts are UNPADDED (glds requirement); bank conflicts broken by a
// 16B-chunk XOR swizzle applied on the global-address side:
//   A (bf16, 128 B/row, 8 chunks):  phys p = c ^ (row & 7)
//   B (fp32, 256 B/row, 16 chunks): phys p = c ^ (row & 15)
// ---------------------------------------------------------------------------
#define BM 128
#define BN 64
#define BK 64
#define NT (DIM / BK)   // 32

__global__ __launch_bounds__(256, 2) void gemm_kernel(
    const unsigned short* __restrict__ X,   // [256][2048] bf16
    const float* __restrict__ V,            // [16384][2048] fp32
    float* __restrict__ C) {                // [256][16384] fp32
  __shared__ __align__(16) unsigned short As[2][BM * BK];  // 2 x 16 KB
  __shared__ __align__(16) float          Bs[2][BN * BK];  // 2 x 16 KB
  const int t  = threadIdx.x;
  const int m0 = blockIdx.x * BM;
  const int n0 = blockIdx.y * BN;
  const int lane = t & 63;
  const int w    = t >> 6;
  const int wm   = (w >> 1) * 64;   // 0,64
  const int wn   = (w & 1) * 32;    // 0,32
  const int fr   = lane & 15;
  const int fko  = lane >> 4;       // 0..3

  f32x4 acc[4][2];
#pragma unroll
  for (int i = 0; i < 4; i++)
#pragma unroll
    for (int j = 0; j < 2; j++) acc[i][j] = (f32x4){0.f, 0.f, 0.f, 0.f};

  // glds per-lane global source addresses (swizzled):
  // A: wave w instr q covers rows w*32+q*8 .. +8 (8 rows x 128 B = 1024 B)
  //    lane l -> row +l/8, phys chunk l%8, logical chunk (l%8)^(l/8)
  const unsigned short* Abase =
      X + (size_t)(m0 + w * 32 + (lane >> 3)) * DIM + ((lane & 7) ^ (lane >> 3)) * 8;
  // B: wave w instr q covers rows w*16+q*4 .. +4 (4 rows x 256 B = 1024 B)
  //    lane l -> row +l/16, phys chunk l%16, logical chunk (l%16)^(l/16)^(q*4)
  const float* Bbase = V + (size_t)(n0 + w * 16 + (lane >> 4)) * DIM;
  const int cB = (lane & 15) ^ (lane >> 4);

  auto glds_tile = [&](int buf, int k0) {
#pragma unroll
    for (int q = 0; q < 4; q++) {
      __builtin_amdgcn_global_load_lds(
          (const AS_GLOBAL unsigned int*)(Abase + (size_t)q * 8 * DIM + k0),
          (AS_LDS unsigned int*)&As[buf][(w * 32 + q * 8) * BK],
          16, 0, 0);
    }
#pragma unroll
    for (int q = 0; q < 4; q++) {
      const int c = cB ^ (q * 4);
      __builtin_amdgcn_global_load_lds(
          (const AS_GLOBAL unsigned int*)(Bbase + (size_t)q * 4 * DIM + k0 + c * 4),
          (AS_LDS unsigned int*)&Bs[buf][(w * 16 + q * 4) * BK],
          16, 0, 0);
    }
  };

  auto compute = [&](int buf) {
#pragma unroll
    for (int kk = 0; kk < BK; kk += 32) {
      bf16x8 aF[4], bF[2];
#pragma unroll
      for (int i = 0; i < 4; i++) {
        const int R  = wm + i * 16 + fr;
        const int c0 = (kk >> 3) + fko;          // logical 16B chunk
        const int p  = c0 ^ (fr & 7);            // swizzled phys chunk
        aF[i] = *(const bf16x8*)&As[buf][R * BK + p * 8];
      }
#pragma unroll
      for (int j = 0; j < 2; j++) {
        const int RN = wn + j * 16 + fr;
        const int c0 = (kk + fko * 8) >> 2;      // even; pair (c0, c0+1)
        const int p0 = c0 ^ fr, p1 = (c0 + 1) ^ fr;
        const float4* Brow = (const float4*)&Bs[buf][RN * BK];
        const float4 lo = Brow[p0];
        const float4 hi = Brow[p1];
        uint4 pk;
        pk.x = pk2(lo.x, lo.y); pk.y = pk2(lo.z, lo.w);
        pk.z = pk2(hi.x, hi.y); pk.w = pk2(hi.z, hi.w);
        bF[j] = *(bf16x8*)&pk;
      }
#pragma unroll
      for (int i = 0; i < 4; i++)
#pragma unroll
        for (int j = 0; j < 2; j++)
          acc[i][j] = __builtin_amdgcn_mfma_f32_16x16x32_bf16(aF[i], bF[j], acc[i][j], 0, 0, 0);
    }
  };

  // prologue: tile 0 -> buf0
  glds_tile(0, 0);
  __syncthreads();

  // steady state: constant buffer indices (alias-analysis friendly)
  for (int kt = 0; kt < NT; kt += 2) {
    if (kt + 1 < NT) glds_tile(1, (kt + 1) * BK);
    compute(0);
    __syncthreads();
    if (kt + 2 < NT) glds_tile(0, (kt + 2) * BK);
    compute(1);
    __syncthreads();
  }

  // epilogue: C/D layout col=lane&15, row=(lane>>4)*4+reg  [m89/m91 verified]
  const int cr = (lane >> 4) * 4;
  const int cc = lane & 15;
#pragma unroll
  for (int i = 0; i < 4; i++)
#pragma unroll
    for (int j = 0; j < 2; j++)
#pragma unroll
      for (int r = 0; r < 4; r++)
        C[(size_t)(m0 + wm + i * 16 + cr + r) * NMEM + (n0 + wn + j * 16 + cc)] =
            acc[i][j][r];
}

// ---------------------------------------------------------------------------
// Kernel 3: per-row losses. One block (256 thr) per sample.
//  - intra CE over own camera bank (no max-sub: exp(v*14.3) <= 1.6e6, fp32 ok)
//  - mask 8 positives
//  - EXACT top-50 via 4096-bin LDS histogram + suffix scan; bins above the
//    boundary bin sum directly, boundary bin resolved exactly (few elems)
//  - inter logsumexp over {8 ori, 50 sel}
// ---------------------------------------------------------------------------
__global__ __launch_bounds__(256) void row_loss_kernel(
    const float* __restrict__ logits,
    const int* __restrict__ labels, const int* __restrict__ cams,
    float* __restrict__ ce_out, float* __restrict__ lossk_out) {
  __shared__ float vals[NMEM];      // 64 KB
  __shared__ int   hist[NBIN];      // 16 KB
  __shared__ float red[256];
  __shared__ int   pint[256];
  __shared__ float bl[512];         // boundary-bin value list
  __shared__ int   bcount;
  __shared__ int   bstar_s, cabove_s;

  const int b = blockIdx.x, t = threadIdx.x;
  const float4* src = (const float4*)(logits + (size_t)b * NMEM);
#pragma unroll
  for (int i = 0; i < 16; i++) ((float4*)vals)[t + 256 * i] = src[t + 256 * i];
#pragma unroll
  for (int i = 0; i < NBIN / 256; i++) hist[t + 256 * i] = 0;
  if (t == 0) bcount = 0;
  const int cam = cams[b], label = labels[b];
  __syncthreads();

  // ---- intra CE over [cam*PCLS, +PCLS) ----
  const int s0 = cam * PCLS;
  float S = 0.f;
#pragma unroll
  for (int i = 0; i < 8; i++) S += __expf(vals[s0 + t + 256 * i] * T_INV);
  red[t] = S; __syncthreads();
  for (int s = 128; s > 0; s >>= 1) { if (t < s) red[t] += red[t + s]; __syncthreads(); }
  float ov[CCAM]; float sumo = 0.f;
  if (t == 0) {
    ce_out[b] = logf(red[0]) - vals[s0 + label] * T_INV;
#pragma unroll
    for (int c = 0; c < CCAM; c++) { ov[c] = vals[c * PCLS + label]; sumo += ov[c]; }
  }
  __syncthreads();                 // t0's ov reads done before masking
  if (t < CCAM) vals[t * PCLS + label] = -1e30f;
  __syncthreads();

  // ---- histogram ----
#pragma unroll
  for (int i = 0; i < 64; i++) {
    int bin = binof(vals[t + 256 * i]);
    atomicAdd(&hist[bin], 1);
  }
  __syncthreads();

  // ---- suffix scan: find boundary bin b* with S(b*) >= K > S(b*+1) ----
  int ps = 0;
#pragma unroll
  for (int i = 0; i < 16; i++) ps += hist[t * 16 + i];
  pint[t] = ps; __syncthreads();
  if (t == 0) {
    int cum = 0, bstar = 0, cab = 0;
    for (int tc = 255; tc >= 0; tc--) {
      if (cum + pint[tc] >= KSEL) {
        for (int bi = tc * 16 + 15; bi >= tc * 16; bi--) {
          int h = hist[bi];
          if (cum + h >= KSEL) { bstar = bi; cab = cum; break; }
          cum += h;
        }
        break;
      }
      cum += pint[tc];
    }
    bstar_s = bstar; cabove_s = cab;
  }
  __syncthreads();
  const int bstar = bstar_s;

  // ---- selection pass: sum exp over bins > b*, collect boundary bin ----
  float S2 = 0.f;
#pragma unroll
  for (int i = 0; i < 64; i++) {
    float v = vals[t + 256 * i];
    int bin = binof(v);
    if (bin > bstar) S2 += __expf(v * T_INV);
    else if (bin == bstar) {
      int p = atomicAdd(&bcount, 1);
      if (p < 512) bl[p] = v;
    }
  }
  red[t] = S2; __syncthreads();
  for (int s = 128; s > 0; s >>= 1) { if (t < s) red[t] += red[t + s]; __syncthreads(); }

  if (t == 0) {
    float S2tot = red[0];
    int need = KSEL - cabove_s;
    int bc = min(bcount, 512);
    for (int r = 0; r < need; r++) {         // exact top-(need) of boundary bin
      float mx = -1e30f; int mi = 0;
      for (int i = 0; i < bc; i++) if (bl[i] > mx) { mx = bl[i]; mi = i; }
      S2tot += __expf(mx * T_INV);
      bl[mi] = -1e30f;
    }
#pragma unroll
    for (int c = 0; c < CCAM; c++) S2tot += __expf(ov[c] * T_INV);
    lossk_out[b] = logf(S2tot) - (sumo * T_INV) * (1.0f / CCAM);
  }
}

// ---------------------------------------------------------------------------
// Kernel 4: deterministic per-camera segment means -> 2 scalars.
// ---------------------------------------------------------------------------
__global__ __launch_bounds__(256) void finalize_kernel(
    const float* __restrict__ ce, const float* __restrict__ lossk,
    const int* __restrict__ cams, float* __restrict__ out) {
  __shared__ float ce_s[BATCH], lk_s[BATCH];
  __shared__ int   cam_s[BATCH];
  __shared__ float si[CCAM], sk[CCAM], cnt[CCAM];
  const int t = threadIdx.x;
  ce_s[t]  = ce[t];
  lk_s[t]  = lossk[t];
  cam_s[t] = cams[t];
  __syncthreads();
  if (t < CCAM) {
    float a = 0.f, b = 0.f; int n = 0;
    for (int i = 0; i < BATCH; i++) {
      if (cam_s[i] == t) { a += ce_s[i]; b += lk_s[i]; n++; }
    }
    si[t] = a; sk[t] = b; cnt[t] = (float)n;
  }
  __syncthreads();
  if (t == 0) {
    float li = 0.f, lk = 0.f;
    for (int c = 0; c < CCAM; c++) {
      if (cnt[c] > 0.f) { li += si[c] / cnt[c]; lk += sk[c] / cnt[c]; }
    }
    out[0] = li;
    out[1] = 0.5f * lk;
  }
}

// ---------------------------------------------------------------------------
extern "C" void kernel_launch(void* const* d_in, const int* in_sizes, int n_in,
                              void* d_out, int out_size, void* d_ws, size_t ws_size,
                              hipStream_t stream) {
  const float* inputs = (const float*)d_in[0];   // [256][2048]
  const int*   labels = (const int*)d_in[1];     // [256]
  const int*   cams   = (const int*)d_in[2];     // [256]
  const float* tempV  = (const float*)d_in[3];   // [16384][2048]
  float* out = (float*)d_out;

  char* ws = (char*)d_ws;
  unsigned short* xb  = (unsigned short*)ws;                       // 1 MB
  float* logits       = (float*)(ws + (1u << 20));                 // 16 MB
  float* ce           = (float*)(ws + (1u << 20) + (16u << 20));   // 1 KB
  float* lossk        = (float*)(ws + (1u << 20) + (16u << 20) + 1024);

  norm_cast_kernel<<<BATCH, 256, 0, stream>>>(inputs, xb);
  gemm_kernel<<<dim3(BATCH / BM, NMEM / BN), 256, 0, stream>>>(xb, tempV, logits);
  row_loss_kernel<<<BATCH, 256, 0, stream>>>(logits, labels, cams, ce, lossk);
  finalize_kernel<<<1, 256, 0, stream>>>(ce, lossk, cams, out);
}

// Round 7
// 275.326 us; speedup vs baseline: 1.1840x; 1.0007x over previous
//
#include <hip/hip_runtime.h>
#include <hip/hip_bf16.h>

// Problem constants
#define BATCH 256
#define DIM   2048
#define NMEM  16384   // C_CAM * P
#define PCLS  2048
#define CCAM  8
#define KSEL  50
#define T_INV 14.285714285714285714f   // 1 / 0.07
#define NBIN  4096

typedef __bf16 bf16x8 __attribute__((ext_vector_type(8)));
typedef float  f32x4  __attribute__((ext_vector_type(4)));

#define AS_GLOBAL __attribute__((address_space(1)))
#define AS_LDS    __attribute__((address_space(3)))

static __device__ __forceinline__ unsigned int f2bf(float f) {
  unsigned int u = __float_as_uint(f);
  return (u + 0x7FFFu + ((u >> 16) & 1u)) >> 16;   // RNE truncate to bf16
}
static __device__ __forceinline__ unsigned int pk2(float lo, float hi) {
  return f2bf(lo) | (f2bf(hi) << 16);
}
// logits are cosine sims in [-1,1]; map to bin 0..4095 (masked -1e30 -> bin 0)
static __device__ __forceinline__ int binof(float v) {
  float bf = fmaf(v, 1950.4762f, 2048.0f);     // 4096 / 2.1 scale
  bf = fminf(fmaxf(bf, 0.0f), 4095.0f);
  return (int)bf;
}

// ---------------------------------------------------------------------------
// Kernel 1: row-normalize inputs, cast to bf16.  grid=256 blocks x 256 thr
// ---------------------------------------------------------------------------
__global__ __launch_bounds__(256) void norm_cast_kernel(
    const float* __restrict__ in, unsigned short* __restrict__ xb) {
  __shared__ float red[256];
  const int b = blockIdx.x, t = threadIdx.x;
  const float4* row = (const float4*)(in + (size_t)b * DIM);
  float4 a0 = row[t];
  float4 a1 = row[t + 256];
  float ss = a0.x*a0.x + a0.y*a0.y + a0.z*a0.z + a0.w*a0.w
           + a1.x*a1.x + a1.y*a1.y + a1.z*a1.z + a1.w*a1.w;
  red[t] = ss; __syncthreads();
  for (int s = 128; s > 0; s >>= 1) { if (t < s) red[t] += red[t + s]; __syncthreads(); }
  const float rn = rsqrtf(red[0]);
  ushort4 o0, o1;
  o0.x = (unsigned short)f2bf(a0.x*rn); o0.y = (unsigned short)f2bf(a0.y*rn);
  o0.z = (unsigned short)f2bf(a0.z*rn); o0.w = (unsigned short)f2bf(a0.w*rn);
  o1.x = (unsigned short)f2bf(a1.x*rn); o1.y = (unsigned short)f2bf(a1.y*rn);
  o1.z = (unsigned short)f2bf(a1.z*rn); o1.w = (unsigned short)f2bf(a1.w*rn);
  *(ushort4*)&xb[(size_t)b * DIM + t * 4]         = o0;
  *(ushort4*)&xb[(size_t)b * DIM + (t + 256) * 4] = o1;
}

// ---------------------------------------------------------------------------
// Kernel 2: logits += x(bf16) @ tempV^T over a K-half, tempV staged fp32 via
// global_load_lds (width 16), bf16-converted at fragment-read time.
// BM=128, BN=64, BK=64, 256 thr = 4 waves (2Mx2N), wave tile 64x32.
// SINGLE-buffer LDS (32 KB), m97-style 2-barrier K-loop; latency drain is
// covered by co-residency: grid = dim3(2, 256, 2 Ksplit) = 1024 blocks
// -> 4 blocks/CU, 4 independent barrier domains.
// C accumulated with fp32 atomic add (exactly 2 commutative addends/elem ->
// deterministic); logits must be zeroed before launch (hipMemsetAsync).
// LDS unpadded (glds requirement); conflicts broken by 16B-chunk XOR swizzle
// on the global-address side (verified 0 conflicts in R6):
//   A (bf16, 128 B/row, 8 chunks):  phys p = c ^ (row & 7)
//   B (fp32, 256 B/row, 16 chunks): phys p = c ^ (row & 15)
// ---------------------------------------------------------------------------
#define BM 128
#define BN 64
#define BK 64
#define KHALF (DIM / 2)      // 1024
#define NTH   (KHALF / BK)   // 16 tiles per block

__global__ __launch_bounds__(256, 4) void gemm_kernel(
    const unsigned short* __restrict__ X,   // [256][2048] bf16
    const float* __restrict__ V,            // [16384][2048] fp32
    float* __restrict__ C) {                // [256][16384] fp32 (pre-zeroed)
  __shared__ __align__(16) unsigned short As[BM * BK];  // 16 KB
  __shared__ __align__(16) float          Bs[BN * BK];  // 16 KB
  const int t  = threadIdx.x;
  const int m0 = blockIdx.x * BM;
  const int n0 = blockIdx.y * BN;
  const int kb = blockIdx.z * KHALF;
  const int lane = t & 63;
  const int w    = t >> 6;
  const int wm   = (w >> 1) * 64;   // 0,64
  const int wn   = (w & 1) * 32;    // 0,32
  const int fr   = lane & 15;
  const int fko  = lane >> 4;       // 0..3

  f32x4 acc[4][2];
#pragma unroll
  for (int i = 0; i < 4; i++)
#pragma unroll
    for (int j = 0; j < 2; j++) acc[i][j] = (f32x4){0.f, 0.f, 0.f, 0.f};

  // glds per-lane global source addresses (swizzled):
  // A: wave w instr q covers rows w*32+q*8 .. +8 (8 rows x 128 B = 1024 B)
  //    lane l -> row +l/8, phys chunk l%8, logical chunk (l%8)^(l/8)
  const unsigned short* Abase =
      X + (size_t)(m0 + w * 32 + (lane >> 3)) * DIM + kb
        + ((lane & 7) ^ (lane >> 3)) * 8;
  // B: wave w instr q covers rows w*16+q*4 .. +4 (4 rows x 256 B = 1024 B)
  //    lane l -> row +l/16, phys chunk l%16, logical chunk (l%16)^(l/16)^(q*4)
  const float* Bbase = V + (size_t)(n0 + w * 16 + (lane >> 4)) * DIM + kb;
  const int cB = (lane & 15) ^ (lane >> 4);

  for (int kt = 0; kt < NTH; kt++) {
    const int k0 = kt * BK;
    // ---- stage tile kt into LDS (no VGPR round trip) ----
#pragma unroll
    for (int q = 0; q < 4; q++) {
      __builtin_amdgcn_global_load_lds(
          (const AS_GLOBAL unsigned int*)(Abase + (size_t)q * 8 * DIM + k0),
          (AS_LDS unsigned int*)&As[(w * 32 + q * 8) * BK],
          16, 0, 0);
    }
#pragma unroll
    for (int q = 0; q < 4; q++) {
      const int c = cB ^ (q * 4);
      __builtin_amdgcn_global_load_lds(
          (const AS_GLOBAL unsigned int*)(Bbase + (size_t)q * 4 * DIM + k0 + c * 4),
          (AS_LDS unsigned int*)&Bs[(w * 16 + q * 4) * BK],
          16, 0, 0);
    }
    __syncthreads();   // drains vmcnt -> LDS tile ready

    // ---- compute tile ----
#pragma unroll
    for (int kk = 0; kk < BK; kk += 32) {
      bf16x8 aF[4], bF[2];
#pragma unroll
      for (int i = 0; i < 4; i++) {
        const int R  = wm + i * 16 + fr;
        const int c0 = (kk >> 3) + fko;          // logical 16B chunk
        const int p  = c0 ^ (fr & 7);            // swizzled phys chunk
        aF[i] = *(const bf16x8*)&As[R * BK + p * 8];
      }
#pragma unroll
      for (int j = 0; j < 2; j++) {
        const int RN = wn + j * 16 + fr;
        const int c0 = (kk + fko * 8) >> 2;      // even; pair (c0, c0+1)
        const int p0 = c0 ^ fr, p1 = (c0 + 1) ^ fr;
        const float4* Brow = (const float4*)&Bs[RN * BK];
        const float4 lo = Brow[p0];
        const float4 hi = Brow[p1];
        uint4 pk;
        pk.x = pk2(lo.x, lo.y); pk.y = pk2(lo.z, lo.w);
        pk.z = pk2(hi.x, hi.y); pk.w = pk2(hi.z, hi.w);
        bF[j] = *(bf16x8*)&pk;
      }
#pragma unroll
      for (int i = 0; i < 4; i++)
#pragma unroll
        for (int j = 0; j < 2; j++)
          acc[i][j] = __builtin_amdgcn_mfma_f32_16x16x32_bf16(aF[i], bF[j], acc[i][j], 0, 0, 0);
    }
    __syncthreads();   // all waves done reading before next glds overwrite
  }

  // epilogue: C/D layout col=lane&15, row=(lane>>4)*4+reg  [m89/m91 verified]
  // fp32 atomic add: 2 addends per element, commutative -> deterministic.
  const int cr = (lane >> 4) * 4;
  const int cc = lane & 15;
#pragma unroll
  for (int i = 0; i < 4; i++)
#pragma unroll
    for (int j = 0; j < 2; j++)
#pragma unroll
      for (int r = 0; r < 4; r++)
        unsafeAtomicAdd(
            &C[(size_t)(m0 + wm + i * 16 + cr + r) * NMEM + (n0 + wn + j * 16 + cc)],
            acc[i][j][r]);
}

// ---------------------------------------------------------------------------
// Kernel 3: per-row losses. One block (256 thr) per sample.
//  - intra CE over own camera bank (no max-sub: exp(v*14.3) <= 1.6e6, fp32 ok)
//  - mask 8 positives
//  - EXACT top-50 via 4096-bin LDS histogram + suffix scan; bins above the
//    boundary bin sum directly, boundary bin resolved exactly (few elems)
//  - inter logsumexp over {8 ori, 50 sel}
// ---------------------------------------------------------------------------
__global__ __launch_bounds__(256) void row_loss_kernel(
    const float* __restrict__ logits,
    const int* __restrict__ labels, const int* __restrict__ cams,
    float* __restrict__ ce_out, float* __restrict__ lossk_out) {
  __shared__ float vals[NMEM];      // 64 KB
  __shared__ int   hist[NBIN];      // 16 KB
  __shared__ float red[256];
  __shared__ int   pint[256];
  __shared__ float bl[512];         // boundary-bin value list
  __shared__ int   bcount;
  __shared__ int   bstar_s, cabove_s;

  const int b = blockIdx.x, t = threadIdx.x;
  const float4* src = (const float4*)(logits + (size_t)b * NMEM);
#pragma unroll
  for (int i = 0; i < 16; i++) ((float4*)vals)[t + 256 * i] = src[t + 256 * i];
#pragma unroll
  for (int i = 0; i < NBIN / 256; i++) hist[t + 256 * i] = 0;
  if (t == 0) bcount = 0;
  const int cam = cams[b], label = labels[b];
  __syncthreads();

  // ---- intra CE over [cam*PCLS, +PCLS) ----
  const int s0 = cam * PCLS;
  float S = 0.f;
#pragma unroll
  for (int i = 0; i < 8; i++) S += __expf(vals[s0 + t + 256 * i] * T_INV);
  red[t] = S; __syncthreads();
  for (int s = 128; s > 0; s >>= 1) { if (t < s) red[t] += red[t + s]; __syncthreads(); }
  float ov[CCAM]; float sumo = 0.f;
  if (t == 0) {
    ce_out[b] = logf(red[0]) - vals[s0 + label] * T_INV;
#pragma unroll
    for (int c = 0; c < CCAM; c++) { ov[c] = vals[c * PCLS + label]; sumo += ov[c]; }
  }
  __syncthreads();                 // t0's ov reads done before masking
  if (t < CCAM) vals[t * PCLS + label] = -1e30f;
  __syncthreads();

  // ---- histogram ----
#pragma unroll
  for (int i = 0; i < 64; i++) {
    int bin = binof(vals[t + 256 * i]);
    atomicAdd(&hist[bin], 1);
  }
  __syncthreads();

  // ---- suffix scan: find boundary bin b* with S(b*) >= K > S(b*+1) ----
  int ps = 0;
#pragma unroll
  for (int i = 0; i < 16; i++) ps += hist[t * 16 + i];
  pint[t] = ps; __syncthreads();
  if (t == 0) {
    int cum = 0, bstar = 0, cab = 0;
    for (int tc = 255; tc >= 0; tc--) {
      if (cum + pint[tc] >= KSEL) {
        for (int bi = tc * 16 + 15; bi >= tc * 16; bi--) {
          int h = hist[bi];
          if (cum + h >= KSEL) { bstar = bi; cab = cum; break; }
          cum += h;
        }
        break;
      }
      cum += pint[tc];
    }
    bstar_s = bstar; cabove_s = cab;
  }
  __syncthreads();
  const int bstar = bstar_s;

  // ---- selection pass: sum exp over bins > b*, collect boundary bin ----
  float S2 = 0.f;
#pragma unroll
  for (int i = 0; i < 64; i++) {
    float v = vals[t + 256 * i];
    int bin = binof(v);
    if (bin > bstar) S2 += __expf(v * T_INV);
    else if (bin == bstar) {
      int p = atomicAdd(&bcount, 1);
      if (p < 512) bl[p] = v;
    }
  }
  red[t] = S2; __syncthreads();
  for (int s = 128; s > 0; s >>= 1) { if (t < s) red[t] += red[t + s]; __syncthreads(); }

  if (t == 0) {
    float S2tot = red[0];
    int need = KSEL - cabove_s;
    int bc = min(bcount, 512);
    for (int r = 0; r < need; r++) {         // exact top-(need) of boundary bin
      float mx = -1e30f; int mi = 0;
      for (int i = 0; i < bc; i++) if (bl[i] > mx) { mx = bl[i]; mi = i; }
      S2tot += __expf(mx * T_INV);
      bl[mi] = -1e30f;
    }
#pragma unroll
    for (int c = 0; c < CCAM; c++) S2tot += __expf(ov[c] * T_INV);
    lossk_out[b] = logf(S2tot) - (sumo * T_INV) * (1.0f / CCAM);
  }
}

// ---------------------------------------------------------------------------
// Kernel 4: deterministic per-camera segment means -> 2 scalars.
// ---------------------------------------------------------------------------
__global__ __launch_bounds__(256) void finalize_kernel(
    const float* __restrict__ ce, const float* __restrict__ lossk,
    const int* __restrict__ cams, float* __restrict__ out) {
  __shared__ float ce_s[BATCH], lk_s[BATCH];
  __shared__ int   cam_s[BATCH];
  __shared__ float si[CCAM], sk[CCAM], cnt[CCAM];
  const int t = threadIdx.x;
  ce_s[t]  = ce[t];
  lk_s[t]  = lossk[t];
  cam_s[t] = cams[t];
  __syncthreads();
  if (t < CCAM) {
    float a = 0.f, b = 0.f; int n = 0;
    for (int i = 0; i < BATCH; i++) {
      if (cam_s[i] == t) { a += ce_s[i]; b += lk_s[i]; n++; }
    }
    si[t] = a; sk[t] = b; cnt[t] = (float)n;
  }
  __syncthreads();
  if (t == 0) {
    float li = 0.f, lk = 0.f;
    for (int c = 0; c < CCAM; c++) {
      if (cnt[c] > 0.f) { li += si[c] / cnt[c]; lk += sk[c] / cnt[c]; }
    }
    out[0] = li;
    out[1] = 0.5f * lk;
  }
}

// ---------------------------------------------------------------------------
extern "C" void kernel_launch(void* const* d_in, const int* in_sizes, int n_in,
                              void* d_out, int out_size, void* d_ws, size_t ws_size,
                              hipStream_t stream) {
  const float* inputs = (const float*)d_in[0];   // [256][2048]
  const int*   labels = (const int*)d_in[1];     // [256]
  const int*   cams   = (const int*)d_in[2];     // [256]
  const float* tempV  = (const float*)d_in[3];   // [16384][2048]
  float* out = (float*)d_out;

  char* ws = (char*)d_ws;
  unsigned short* xb  = (unsigned short*)ws;                       // 1 MB
  float* logits       = (float*)(ws + (1u << 20));                 // 16 MB
  float* ce           = (float*)(ws + (1u << 20) + (16u << 20));   // 1 KB
  float* lossk        = (float*)(ws + (1u << 20) + (16u << 20) + 1024);

  norm_cast_kernel<<<BATCH, 256, 0, stream>>>(inputs, xb);
  hipMemsetAsync(logits, 0, (size_t)BATCH * NMEM * sizeof(float), stream);
  gemm_kernel<<<dim3(BATCH / BM, NMEM / BN, 2), 256, 0, stream>>>(xb, tempV, logits);
  row_loss_kernel<<<BATCH, 256, 0, stream>>>(logits, labels, cams, ce, lossk);
  finalize_kernel<<<1, 256, 0, stream>>>(ce, lossk, cams, out);
}